// Round 7
// baseline (172.942 us; speedup 1.0000x reference)
//
#include <hip/hip_runtime.h>
#include <hip/hip_bf16.h>

#define NPIX 4096
#define FEAT 128
#define LAT 64
#define BS 64
#define NSTEPS 6

// flat f32 output offsets (log_m_k, log_s_k, c_f, delta, seeds)
#define OFF_LOGM  0u
#define OFF_LOGS  1835008u
#define OFF_CF    3670016u
#define OFF_DELTA 20447232u
#define OFF_SEEDS 20971520u

typedef float f32x4 __attribute__((ext_vector_type(4)));
typedef short s16x8 __attribute__((ext_vector_type(8)));
typedef unsigned long long u64;

__device__ __forceinline__ void amax_comb(float& bv, int& bi, float v, int i) {
    if (v > bv || (v == bv && i < bi)) { bv = v; bi = i; }
}

// pack (prob, idx) so u64 max == (max prob, tie -> lowest idx). prob >= 0.
__device__ __forceinline__ u64 pack_pi(float v, int idx) {
    return ((u64)__builtin_bit_cast(unsigned, v) << 32) | (unsigned)(~idx);
}

__device__ __forceinline__ short f2bf_rne(float r) {
    __hip_bfloat16 h = __float2bfloat16(r);
    return __builtin_bit_cast(short, h);
}

// split f32 into bf16 hi (truncated -> exact residual) + bf16 lo (RNE of residual)
__device__ __forceinline__ void split2(float v, short& hi, short& lo) {
    unsigned u = __builtin_bit_cast(unsigned, v);
    hi = (short)(u >> 16);
    float hf = __builtin_bit_cast(float, u & 0xFFFF0000u);
    lo = f2bf_rne(v - hf);
}

// 4x4 transpose among the 4 lanes of a quad (b = lane&3).
__device__ __forceinline__ void transpose4(float4& v, int b) {
    float4 w;
    w.x = __shfl_xor(v.x, 1, 64); w.y = __shfl_xor(v.y, 1, 64);
    w.z = __shfl_xor(v.z, 1, 64); w.w = __shfl_xor(v.w, 1, 64);
    float4 u;
    if ((b & 1) == 0) u = make_float4(v.x, w.x, v.z, w.z);
    else              u = make_float4(w.y, v.y, w.w, v.w);
    float4 w2;
    w2.x = __shfl_xor(u.x, 2, 64); w2.y = __shfl_xor(u.y, 2, 64);
    w2.z = __shfl_xor(u.z, 2, 64); w2.w = __shfl_xor(u.w, 2, 64);
    if ((b & 2) == 0) v = make_float4(u.x, u.y, w2.x, w2.y);
    else              v = make_float4(w2.z, w2.w, u.z, u.w);
}

// ---------------------------------------------------------------------------
// K0: split gate*W into bf16 hi/lo scratch; zero amax slots + quorum counters.
// ---------------------------------------------------------------------------
__global__ void prep_w(const float* __restrict__ w, const float* __restrict__ gate_p,
                       short* __restrict__ gwh, short* __restrict__ gwl,
                       u64* __restrict__ amax, int* __restrict__ cnt)
{
    int i = blockIdx.x * 256 + threadIdx.x;   // 8192 total
    float v = gate_p[0] * w[i];
    short h, l; split2(v, h, l);
    gwh[i] = h; gwl[i] = l;
    if (i < NSTEPS * BS) amax[i] = 0ull;
    if (i < BS * 8)      cnt[i]  = 0;
}

// ---------------------------------------------------------------------------
// K1: 1x1 conv via split-bf16 MFMA. SMALL wave tile: 16 px x 64 outs per wave
// (acc = 16 regs), block = 4 waves = 64 px, grid = 64 b x 64 tiles = 4096.
// 4 blocks/CU (launch_bounds cap 128 VGPR) -> latency hidden by occupancy.
// Quad-transposed float4 loads land directly in B-fragment order (proven).
// ---------------------------------------------------------------------------
__global__ __launch_bounds__(256, 4) void conv_mfma(
    const float* __restrict__ x, const float* __restrict__ rand_pixel,
    const float* __restrict__ bias, const float* __restrict__ gate_p,
    float* __restrict__ out, u64* __restrict__ amax,
    const short* __restrict__ gwh, const short* __restrict__ gwl)
{
    __shared__ float sbias[64];

    const int tid  = threadIdx.x;
    const int b    = blockIdx.x >> 6;
    const int t    = blockIdx.x & 63;
    const int p0   = t * 64;
    const int lane = tid & 63;
    const int wv   = tid >> 6;
    const int l15  = lane & 15;
    const int lg   = lane >> 4;
    const int j    = l15 & 3;

    if (tid < 64) sbias[tid] = gate_p[0] * bias[tid];
    __syncthreads();

    f32x4 acc[4];
    #pragma unroll
    for (int og = 0; og < 4; ++og) acc[og] = (f32x4){0.f, 0.f, 0.f, 0.f};

    // lane base: feat lg*8+j, px block (l15&~3) within the wave's 16 px
    const float* xq = x + (size_t)b * FEAT * NPIX
                        + (size_t)(lg * 8 + j) * NPIX
                        + p0 + wv * 16 + (l15 & ~3);

    float4 buf[2][2];
    buf[0][0] = *(const float4*)(xq);
    buf[0][1] = *(const float4*)(xq + (size_t)4 * NPIX);

    #pragma unroll
    for (int kc = 0; kc < 4; ++kc) {
        const int cur = kc & 1;
        if (kc < 3) {
            buf[cur ^ 1][0] = *(const float4*)(xq + (size_t)((kc + 1) * 32) * NPIX);
            buf[cur ^ 1][1] = *(const float4*)(xq + (size_t)((kc + 1) * 32 + 4) * NPIX);
        }

        s16x8 Ah[4], Al[4];
        #pragma unroll
        for (int og = 0; og < 4; ++og) {
            Ah[og] = *(const s16x8*)&gwh[(og * 16 + l15) * 128 + kc * 32 + lg * 8];
            Al[og] = *(const s16x8*)&gwl[(og * 16 + l15) * 128 + kc * 32 + lg * 8];
        }

        float4 t0 = buf[cur][0];
        float4 t1 = buf[cur][1];
        transpose4(t0, j);   // lane: own px (l15), feats kc*32+lg*8+0..3
        transpose4(t1, j);   // feats +4..7
        s16x8 Bh, Bl;
        short h, l;
        split2(t0.x, h, l); Bh[0] = h; Bl[0] = l;
        split2(t0.y, h, l); Bh[1] = h; Bl[1] = l;
        split2(t0.z, h, l); Bh[2] = h; Bl[2] = l;
        split2(t0.w, h, l); Bh[3] = h; Bl[3] = l;
        split2(t1.x, h, l); Bh[4] = h; Bl[4] = l;
        split2(t1.y, h, l); Bh[5] = h; Bl[5] = l;
        split2(t1.z, h, l); Bh[6] = h; Bl[6] = l;
        split2(t1.w, h, l); Bh[7] = h; Bl[7] = l;

        #pragma unroll
        for (int og = 0; og < 4; ++og) {
            acc[og] = __builtin_amdgcn_mfma_f32_16x16x32_bf16(Ah[og], Bh, acc[og], 0, 0, 0);
            acc[og] = __builtin_amdgcn_mfma_f32_16x16x32_bf16(Ah[og], Bl, acc[og], 0, 0, 0);
            acc[og] = __builtin_amdgcn_mfma_f32_16x16x32_bf16(Al[og], Bh, acc[og], 0, 0, 0);
        }
    }

    // epilogue: D mapping col=l15 (pixel), row=4*lg+r
    float* cf = out + OFF_CF + (size_t)b * LAT * NPIX;
    const int p = p0 + wv * 16 + l15;
    #pragma unroll
    for (int og = 0; og < 4; ++og) {
        #pragma unroll
        for (int r = 0; r < 4; ++r) {
            int o = og * 16 + lg * 4 + r;
            float v = acc[og][r] + sbias[o];
            if (o == 62) {
                out[OFF_DELTA + ((size_t)b * 2 + 0) * NPIX + p] = v;
                v += (float)(-1.0 + 2.0 * (double)(p >> 6) / 63.0);
            } else if (o == 63) {
                out[OFF_DELTA + ((size_t)b * 2 + 1) * NPIX + p] = v;
                v += (float)(-1.0 + 2.0 * (double)(p & 63) / 63.0);
            }
            cf[(size_t)o * NPIX + p] = v;
        }
    }

    // block extras: zero log_s_k[0] for this tile; step-0 argmax partial
    if (wv == 0) {
        if (lane < 16)
            *(float4*)(out + OFF_LOGS + (size_t)b * NPIX + p0 + lane * 4) =
                make_float4(0.f, 0.f, 0.f, 0.f);
        float bv = rand_pixel[(size_t)b * NPIX + p0 + lane];
        int   bi = p0 + lane;
        #pragma unroll
        for (int off = 32; off > 0; off >>= 1) {
            float ov = __shfl_down(bv, off, 64);
            int   oi = __shfl_down(bi, off, 64);
            amax_comb(bv, bi, ov, oi);
        }
        if (lane == 0) atomicMax(&amax[b], pack_pi(bv, bi));
    }
}

// named-register c_f: 16 x f32x4 per thread
#define REP16(OP) OP(0) OP(1) OP(2) OP(3) OP(4) OP(5) OP(6) OP(7) \
                  OP(8) OP(9) OP(10) OP(11) OP(12) OP(13) OP(14) OP(15)

// ---------------------------------------------------------------------------
// K2: fused 6-step clustering. Block = 1024 thr = 1024 px, grid 256.
// launch_bounds(1024,4) -> 128 VGPR cap so cr[64] stays register-resident
// (round-4/6 capped at 64 -> spilled). Packed-u64 atomicMax argmax slots;
// per-batch quorum-4 spin sync.
// ---------------------------------------------------------------------------
__global__ __launch_bounds__(1024, 4) void steps_fused(
    const float* __restrict__ rand_pixel, const float* __restrict__ log_sigma_p,
    float* __restrict__ out, u64* amax, int* cnt)
{
    __shared__ __align__(16) float s_seed[LAT];
    __shared__ float s_rv[16];
    __shared__ int   s_ri[16];
    __shared__ u64   s_m;

    const int tid  = threadIdx.x;
    const int b    = blockIdx.x >> 2;
    const int tile = blockIdx.x & 3;
    const int p    = tile * 1024 + tid;

    const float* cfb = out + OFF_CF + (size_t)b * LAT * NPIX;

#define DECLR(i) f32x4 r##i;
    REP16(DECLR)
#define LOADR(i) r##i = (f32x4){ cfb[(size_t)(4*i+0)*NPIX + p], cfb[(size_t)(4*i+1)*NPIX + p], \
                                 cfb[(size_t)(4*i+2)*NPIX + p], cfb[(size_t)(4*i+3)*NPIX + p] };
    REP16(LOADR)

    f32x4 aq = r0 * r0;
#define SQR(i) aq += r##i * r##i;
    SQR(1) SQR(2) SQR(3) SQR(4) SQR(5) SQR(6) SQR(7)
    SQR(8) SQR(9) SQR(10) SQR(11) SQR(12) SQR(13) SQR(14) SQR(15)
    const float cr2 = aq[0] + aq[1] + aq[2] + aq[3];

    const float rp    = rand_pixel[(size_t)b * NPIX + p];
    const float sigma = expf(log_sigma_p[0]);
    float ls = 0.f;

    #pragma unroll 1
    for (int s = 0; s < NSTEPS; ++s) {
        if (s > 0) {
            if (tid == 0) {
                while (__hip_atomic_load(&cnt[b * 8 + s], __ATOMIC_ACQUIRE,
                                         __HIP_MEMORY_SCOPE_AGENT) < 4)
                    __builtin_amdgcn_s_sleep(2);
            }
            __syncthreads();
        }
        if (tid == 0)
            s_m = __hip_atomic_load(&amax[s * BS + b], __ATOMIC_RELAXED,
                                    __HIP_MEMORY_SCOPE_AGENT);
        __syncthreads();
        const int bi = ~(unsigned)(s_m & 0xFFFFFFFFu);

        if (tid < LAT) s_seed[tid] = cfb[(size_t)tid * NPIX + bi];
        __syncthreads();
        if (tile == 0 && tid < LAT)
            out[OFF_SEEDS + ((size_t)s * BS + b) * LAT + tid] = s_seed[tid];

        // d2 = |c|^2 + |s|^2 - 2 c.s
        f32x4 dacc = (f32x4){0.f, 0.f, 0.f, 0.f};
        f32x4 sacc = (f32x4){0.f, 0.f, 0.f, 0.f};
#define DOT(i) { f32x4 sv = *(const f32x4*)&s_seed[4*i]; dacc += r##i * sv; sacc += sv * sv; }
        REP16(DOT)
        float dot = dacc[0] + dacc[1] + dacc[2] + dacc[3];
        float s2  = sacc[0] + sacc[1] + sacc[2] + sacc[3];
        float d2  = cr2 + s2 - 2.0f * dot;

        float dist  = sqrtf(fminf(fmaxf(d2, 1e-10f), 1e10f));
        float alpha = expf(-dist / sigma);
        alpha = fminf(fmaxf(alpha, 0.01f), 0.99f);
        float lm  = ls + logf(alpha);
        float lsn = ls + log1pf(-alpha);

        out[OFF_LOGM + ((size_t)s * BS + b) * NPIX + p]       = lm;
        out[OFF_LOGS + ((size_t)(s + 1) * BS + b) * NPIX + p] = lsn;
        ls = lsn;

        if (s == NSTEPS - 1) {
            out[OFF_LOGM + ((size_t)NSTEPS * BS + b) * NPIX + p] = lsn;
        } else {
            float prob = rp * expf(lsn);
            int   idx  = p;
            #pragma unroll
            for (int off = 32; off > 0; off >>= 1) {
                float ov = __shfl_down(prob, off, 64);
                int   oi = __shfl_down(idx, off, 64);
                amax_comb(prob, idx, ov, oi);
            }
            int lane = tid & 63, wid = tid >> 6;
            if (lane == 0) { s_rv[wid] = prob; s_ri[wid] = idx; }
            __syncthreads();
            if (tid == 0) {
                float fb = s_rv[0]; int fi = s_ri[0];
                #pragma unroll
                for (int k = 1; k < 16; ++k) amax_comb(fb, fi, s_rv[k], s_ri[k]);
                atomicMax(&amax[(s + 1) * BS + b], pack_pi(fb, fi));
                __hip_atomic_fetch_add(&cnt[b * 8 + s + 1], 1,
                                       __ATOMIC_RELEASE, __HIP_MEMORY_SCOPE_AGENT);
            }
        }
    }
}

// ---------------------------------------------------------------------------
// Fallback: per-step kernel (kernel-boundary sync) if coop launch fails.
// ---------------------------------------------------------------------------
__global__ __launch_bounds__(1024, 4) void step_kernel(
    const float* __restrict__ rand_pixel, const float* __restrict__ log_sigma_p,
    float* __restrict__ out, u64* amax, int step)
{
    __shared__ __align__(16) float s_seed[LAT];
    __shared__ float s_rv[16];
    __shared__ int   s_ri[16];

    const int tid  = threadIdx.x;
    const int b    = blockIdx.x >> 2;
    const int tile = blockIdx.x & 3;
    const int p    = tile * 1024 + tid;

    const float* cfb = out + OFF_CF + (size_t)b * LAT * NPIX;

    u64 m = amax[step * BS + b];
    const int bi = ~(unsigned)(m & 0xFFFFFFFFu);

    if (tid < LAT) s_seed[tid] = cfb[(size_t)tid * NPIX + bi];
    __syncthreads();
    if (tile == 0 && tid < LAT)
        out[OFF_SEEDS + ((size_t)step * BS + b) * LAT + tid] = s_seed[tid];

    float d2 = 0.f;
    #pragma unroll
    for (int c = 0; c < LAT; ++c) {
        float d = cfb[(size_t)c * NPIX + p] - s_seed[c];
        d2 = fmaf(d, d, d2);
    }
    float dist  = sqrtf(fminf(fmaxf(d2, 1e-10f), 1e10f));
    float sigma = expf(log_sigma_p[0]);
    float alpha = expf(-dist / sigma);
    alpha = fminf(fmaxf(alpha, 0.01f), 0.99f);

    float ls  = out[OFF_LOGS + ((size_t)step * BS + b) * NPIX + p];
    float lm  = ls + logf(alpha);
    float lsn = ls + log1pf(-alpha);

    out[OFF_LOGM + ((size_t)step * BS + b) * NPIX + p]       = lm;
    out[OFF_LOGS + ((size_t)(step + 1) * BS + b) * NPIX + p] = lsn;
    if (step == NSTEPS - 1)
        out[OFF_LOGM + ((size_t)NSTEPS * BS + b) * NPIX + p] = lsn;

    if (step < NSTEPS - 1) {
        float prob = rand_pixel[(size_t)b * NPIX + p] * expf(lsn);
        int   idx  = p;
        #pragma unroll
        for (int off = 32; off > 0; off >>= 1) {
            float ov = __shfl_down(prob, off, 64);
            int   oi = __shfl_down(idx, off, 64);
            amax_comb(prob, idx, ov, oi);
        }
        int lane = tid & 63, wid = tid >> 6;
        if (lane == 0) { s_rv[wid] = prob; s_ri[wid] = idx; }
        __syncthreads();
        if (tid == 0) {
            float fb = s_rv[0]; int fi = s_ri[0];
            #pragma unroll
            for (int k = 1; k < 16; ++k) amax_comb(fb, fi, s_rv[k], s_ri[k]);
            atomicMax(&amax[(step + 1) * BS + b], pack_pi(fb, fi));
        }
    }
}

extern "C" void kernel_launch(void* const* d_in, const int* in_sizes, int n_in,
                              void* d_out, int out_size, void* d_ws, size_t ws_size,
                              hipStream_t stream) {
    const float* x          = (const float*)d_in[0];
    const float* rand_pixel = (const float*)d_in[1];
    const float* w          = (const float*)d_in[2];
    const float* bias       = (const float*)d_in[3];
    const float* gate       = (const float*)d_in[4];
    const float* log_sigma  = (const float*)d_in[5];

    float* out = (float*)d_out;
    // ws: gwh 16KB | gwl 16KB | amax [6][64] u64 (3KB) | cnt [64][8] i32 (2KB)
    short* gwh  = (short*)d_ws;
    short* gwl  = (short*)((char*)d_ws + 16384);
    u64*   amax = (u64*)((char*)d_ws + 32768);
    int*   cnt  = (int*)((char*)d_ws + 35840);

    prep_w<<<32, 256, 0, stream>>>(w, gate, gwh, gwl, amax, cnt);
    conv_mfma<<<4096, 256, 0, stream>>>(x, rand_pixel, bias, gate, out, amax, gwh, gwl);

    const float* a0 = rand_pixel; const float* a1 = log_sigma; float* a2 = out;
    u64* a3 = amax; int* a4 = cnt;
    void* kp[5] = {(void*)&a0, (void*)&a1, (void*)&a2, (void*)&a3, (void*)&a4};
    hipError_t e = hipLaunchCooperativeKernel((const void*)steps_fused,
                                              dim3(256), dim3(1024), kp, 0, stream);
    if (e != hipSuccess) {
        for (int s = 0; s < NSTEPS; ++s)
            step_kernel<<<256, 1024, 0, stream>>>(rand_pixel, log_sigma, out, amax, s);
    }
}